// Round 4
// baseline (226.689 us; speedup 1.0000x reference)
//
#include <hip/hip_runtime.h>
#include <hip/hip_bf16.h>
#include <stdint.h>

// GAT layer, fused.  B=8, N=2048, F_in=256, F_out=64.
//   k_wh  : Wh = h @ W^T (fp32 LDS-tiled), emits Wh1/Wh2 (fp32) and Wh in
//           bf16 MFMA-B-fragment layout (k_attn B-loads = coalesced dwordx4).
//   k_attn: single pass over adj, 16-row tiles, 4 waves split the j-range.
//           exp factoring: exp(leaky(w1+w2)-C) = max(P1*P2[j], N1*N2[j])
//           with P1=exp(cm-C), N1=exp(0.2cm-C) per-row (both <=1) and
//           P2=exp(w2-M2), N2=exp(0.2(w2-M2)) per-j (both <=1, LDS).
//           -> inner loop has NO transcendentals and cannot overflow.
//           R3/R4: adj loads NON-TEMPORAL via ext_vector int4 (zero reuse;
//           stop evicting whf from L2 -- whf is re-read 268 MB/launch),
//           depth-2 adj prefetch, nt out stores, __launch_bounds__(256,4).

typedef __attribute__((ext_vector_type(8))) short short8;
typedef __attribute__((ext_vector_type(4))) float f32x4;
typedef __attribute__((ext_vector_type(4))) int i32x4;   // nt-load-able

#define GAT_ALPHA 0.2f

__device__ __forceinline__ short f2bf(float x) {  // RNE float->bf16 bits
  union { float f; uint32_t u; } v; v.f = x;
  uint32_t r = v.u + 0x7FFFu + ((v.u >> 16) & 1u);
  return (short)(r >> 16);
}

__device__ __forceinline__ i32x4 ntload4(const int* p) {
  return __builtin_nontemporal_load((const i32x4*)p);
}

// ---------------------------------------------------------------- kernel 1
// grid 512, block 256. 32 rows/block, K split in two 128-phases.
__global__ __launch_bounds__(256) void k_wh(
    const float* __restrict__ h, const float* __restrict__ W,
    const float* __restrict__ a, short* __restrict__ whf,
    float* __restrict__ wh1, float* __restrict__ wh2)
{
  __shared__ float hl[32 * 132];
  __shared__ float Wl[64 * 132];
  const int tid  = threadIdx.x;
  const int og   = tid & 15;   // output group: o = og + 16c
  const int rg   = tid >> 4;   // row group: rows rg*2 + {0,1}
  const int row0 = blockIdx.x << 5;

  float acc[2][4] = {};

  for (int kp = 0; kp < 2; ++kp) {
    if (kp) __syncthreads();
#pragma unroll
    for (int i = 0; i < 4; ++i) {            // stage h 32x128
      int idx4 = tid + (i << 8);
      int row = idx4 >> 5, kc = idx4 & 31;
      *(float4*)&hl[row * 132 + kc * 4] =
          *(const float4*)&h[(size_t)(row0 + row) * 256 + (kp << 7) + kc * 4];
    }
#pragma unroll
    for (int i = 0; i < 8; ++i) {            // stage W 64x128
      int idx4 = tid + (i << 8);
      int o = idx4 >> 5, kc = idx4 & 31;
      *(float4*)&Wl[o * 132 + kc * 4] =
          *(const float4*)&W[o * 256 + (kp << 7) + kc * 4];
    }
    __syncthreads();
#pragma unroll 4
    for (int kc = 0; kc < 32; ++kc) {
      const int k0 = kc * 4;
      const float4 hv0 = *(const float4*)&hl[(rg * 2 + 0) * 132 + k0];
      const float4 hv1 = *(const float4*)&hl[(rg * 2 + 1) * 132 + k0];
#pragma unroll
      for (int c = 0; c < 4; ++c) {
        const float4 wv = *(const float4*)&Wl[(og + (c << 4)) * 132 + k0];
        acc[0][c] += hv0.x * wv.x + hv0.y * wv.y + hv0.z * wv.z + hv0.w * wv.w;
        acc[1][c] += hv1.x * wv.x + hv1.y * wv.y + hv1.z * wv.z + hv1.w * wv.w;
      }
    }
  }

  float a1v[4], a2v[4];
#pragma unroll
  for (int c = 0; c < 4; ++c) {
    a1v[c] = a[og + (c << 4)];
    a2v[c] = a[64 + og + (c << 4)];
  }
#pragma unroll
  for (int r = 0; r < 2; ++r) {
    const int row = row0 + rg * 2 + r;
    const int bb = row >> 11, j = row & 2047;
    const int s = j >> 5, g2 = (j >> 3) & 3, t = j & 7;
    // B-frag layout: idx = b*131072 + ((s*4 + ot)*64 + g2*16 + og)*8 + t
    const size_t base = ((size_t)bb << 17) +
                        (size_t)((s * 256 + g2 * 16 + og) * 8 + t);
    float p1 = 0.f, p2 = 0.f;
#pragma unroll
    for (int c = 0; c < 4; ++c) {
      whf[base + c * 512] = f2bf(acc[r][c]);
      p1 += acc[r][c] * a1v[c];
      p2 += acc[r][c] * a2v[c];
    }
#pragma unroll
    for (int off = 8; off; off >>= 1) {      // reduce over 16-lane og group
      p1 += __shfl_xor(p1, off);
      p2 += __shfl_xor(p2, off);
    }
    if (og == 0) { wh1[row] = p1; wh2[row] = p2; }
  }
}

// ---------------------------------------------------------------- kernel 2
// grid 1024 (= b * 128 i-tiles of 16 rows), block 256 (4 waves).
// wave w handles j in [w*512, (w+1)*512), all 4 o-tiles, 16 rows.
__global__ __launch_bounds__(256, 4) void k_attn(
    const int* __restrict__ adj, const short* __restrict__ whf,
    const float* __restrict__ wh1, const float* __restrict__ wh2,
    float* __restrict__ out)
{
  const int blk = blockIdx.x;
  const int b   = blk >> 7;
  const int i0  = (blk & 127) << 4;
  const int tid = threadIdx.x;
  const int wave = tid >> 6;
  const int lane = tid & 63;
  const int og = lane & 15;    // A-frag row m
  const int g  = lane >> 4;    // A-frag k-quad

  __shared__ __align__(16) float2 pn[2048];  // {P2,N2} per j; reused as red[]
  __shared__ float lred[64];                 // l partial per (wave,row)
  __shared__ float redm[4];

  // ---- phase 1: block max of Wh2[b,:]
  const float* w2g = wh2 + (b << 11);
  float w2r[8];
  float mp = -3.0e38f;
  {
    const float4 v0 = *(const float4*)&w2g[tid << 3];
    const float4 v1 = *(const float4*)&w2g[(tid << 3) + 4];
    w2r[0] = v0.x; w2r[1] = v0.y; w2r[2] = v0.z; w2r[3] = v0.w;
    w2r[4] = v1.x; w2r[5] = v1.y; w2r[6] = v1.z; w2r[7] = v1.w;
#pragma unroll
    for (int t = 0; t < 8; ++t) mp = fmaxf(mp, w2r[t]);
  }
#pragma unroll
  for (int off = 32; off; off >>= 1) mp = fmaxf(mp, __shfl_xor(mp, off));
  if (lane == 0) redm[wave] = mp;
  __syncthreads();
  const float M2 = fmaxf(fmaxf(redm[0], redm[1]), fmaxf(redm[2], redm[3]));

  // ---- phase 2: stage {P2,N2} per j
  {
    float4 st[4];
#pragma unroll
    for (int t = 0; t < 4; ++t) {
      st[t].x = __expf(w2r[2 * t] - M2);
      st[t].y = __expf(GAT_ALPHA * (w2r[2 * t] - M2));
      st[t].z = __expf(w2r[2 * t + 1] - M2);
      st[t].w = __expf(GAT_ALPHA * (w2r[2 * t + 1] - M2));
    }
#pragma unroll
    for (int t = 0; t < 4; ++t)
      *(float4*)&pn[(tid << 3) + 2 * t] = st[t];
  }

  // ---- per-row constants
  const int irow = i0 + og;
  const float w1 = wh1[(b << 11) + irow];
  const float cm = w1 + M2;
  const float C  = fmaxf(cm, GAT_ALPHA * cm);   // exact row-max upper bound
  const float P1 = __expf(cm - C);              // <= 1
  const float N1 = __expf(GAT_ALPHA * cm - C);  // <= 1
  __syncthreads();

  // ---- main loop: 16 steps of 32 j, depth-2 adj prefetch (nt loads)
  const int jbase0 = wave << 9;
  const int* __restrict__ arow =
      adj + ((size_t)((b << 11) + irow) << 11) + jbase0 + (g << 3);
  const short8* __restrict__ fb = (const short8*)whf + (b << 14);
  const float4* __restrict__ pn4 = (const float4*)pn;
  const int pnb = ((jbase0 >> 1) + (g << 2));
  const int fo0 = (jbase0 >> 5) << 2;

  f32x4 acc[4] = {{0.f,0.f,0.f,0.f},{0.f,0.f,0.f,0.f},
                  {0.f,0.f,0.f,0.f},{0.f,0.f,0.f,0.f}};
  float lsum = 0.f;

  i32x4 A0c = ntload4(arow),      A1c = ntload4(arow + 4);
  i32x4 A0n = ntload4(arow + 32), A1n = ntload4(arow + 36);
  short8 B0 = fb[(fo0 + 0) * 64 + lane];
  short8 B1 = fb[(fo0 + 1) * 64 + lane];
  short8 B2 = fb[(fo0 + 2) * 64 + lane];
  short8 B3 = fb[(fo0 + 3) * 64 + lane];

  union Frag { short8 s; __hip_bfloat162 h[4]; };

  auto step = [&](const i32x4 cA0, const i32x4 cA1, const short8 cB0,
                  const short8 cB1, const short8 cB2, const short8 cB3,
                  const int s) {
    const float4 q0 = pn4[pnb + (s << 4) + 0];  // {P2 j0, N2 j0, P2 j1, N2 j1}
    const float4 q1 = pn4[pnb + (s << 4) + 1];
    const float4 q2 = pn4[pnb + (s << 4) + 2];
    const float4 q3 = pn4[pnb + (s << 4) + 3];
    float p[8];
    p[0] = fmaxf(P1 * q0.x, N1 * q0.y); p[1] = fmaxf(P1 * q0.z, N1 * q0.w);
    p[2] = fmaxf(P1 * q1.x, N1 * q1.y); p[3] = fmaxf(P1 * q1.z, N1 * q1.w);
    p[4] = fmaxf(P1 * q2.x, N1 * q2.y); p[5] = fmaxf(P1 * q2.z, N1 * q2.w);
    p[6] = fmaxf(P1 * q3.x, N1 * q3.y); p[7] = fmaxf(P1 * q3.z, N1 * q3.w);
    p[0] = (cA0.x > 0) ? p[0] : 0.f;  p[1] = (cA0.y > 0) ? p[1] : 0.f;
    p[2] = (cA0.z > 0) ? p[2] : 0.f;  p[3] = (cA0.w > 0) ? p[3] : 0.f;
    p[4] = (cA1.x > 0) ? p[4] : 0.f;  p[5] = (cA1.y > 0) ? p[5] : 0.f;
    p[6] = (cA1.z > 0) ? p[6] : 0.f;  p[7] = (cA1.w > 0) ? p[7] : 0.f;
    lsum += ((p[0] + p[1]) + (p[2] + p[3])) + ((p[4] + p[5]) + (p[6] + p[7]));
    Frag af;
#pragma unroll
    for (int t = 0; t < 4; ++t)
      af.h[t] = __float22bfloat162_rn(float2{p[2 * t], p[2 * t + 1]});
    acc[0] = __builtin_amdgcn_mfma_f32_16x16x32_bf16(af.s, cB0, acc[0], 0, 0, 0);
    acc[1] = __builtin_amdgcn_mfma_f32_16x16x32_bf16(af.s, cB1, acc[1], 0, 0, 0);
    acc[2] = __builtin_amdgcn_mfma_f32_16x16x32_bf16(af.s, cB2, acc[2], 0, 0, 0);
    acc[3] = __builtin_amdgcn_mfma_f32_16x16x32_bf16(af.s, cB3, acc[3], 0, 0, 0);
  };

  for (int s = 0; s < 16; ++s) {
    // depth-2 adj prefetch, depth-1 B prefetch (clamped; no branches)
    const int sp = s + 2 < 16 ? s + 2 : 15;
    const int sb = s + 1 < 16 ? s + 1 : 15;
    const int* an = arow + (sp << 5);
    const i32x4 fA0 = ntload4(an);
    const i32x4 fA1 = ntload4(an + 4);
    const int fo = fo0 + (sb << 2);
    const short8 nB0 = fb[(fo + 0) * 64 + lane];
    const short8 nB1 = fb[(fo + 1) * 64 + lane];
    const short8 nB2 = fb[(fo + 2) * 64 + lane];
    const short8 nB3 = fb[(fo + 3) * 64 + lane];
    step(A0c, A1c, B0, B1, B2, B3, s);
    A0c = A0n; A1c = A1n; A0n = fA0; A1n = fA1;
    B0 = nB0; B1 = nB1; B2 = nB2; B3 = nB3;
  }

  // ---- combine j-partials across waves (reuse pn as red[4][16][64])
  lsum += __shfl_xor(lsum, 16);
  lsum += __shfl_xor(lsum, 32);
  if (g == 0) lred[(wave << 4) + og] = lsum;

  __syncthreads();                       // all waves done reading pn
  float* red = (float*)pn;               // red[w*1024 + row*64 + col]
#pragma unroll
  for (int ot = 0; ot < 4; ++ot)
#pragma unroll
    for (int q = 0; q < 4; ++q)
      red[(wave << 10) + ((g << 2) + q) * 64 + (ot << 4) + og] = acc[ot][q];
  __syncthreads();

  // ---- final reduce + epilogue: thread -> col = tid&63, rows rb*4+q
  const int col = tid & 63;
  const int rb  = tid >> 6;
#pragma unroll
  for (int q = 0; q < 4; ++q) {
    const int row = (rb << 2) + q;
    float s = red[row * 64 + col] + red[1024 + row * 64 + col] +
              red[2048 + row * 64 + col] + red[3072 + row * 64 + col];
    const float l = lred[row] + lred[16 + row] + lred[32 + row] + lred[48 + row];
    float v = s / l;
    v = v > 0.f ? v : __expf(v) - 1.0f;          // ELU (alpha=1)
    __builtin_nontemporal_store(
        v, &out[((size_t)((b << 11) + i0 + row) << 6) + col]);
  }
}

extern "C" void kernel_launch(void* const* d_in, const int* in_sizes, int n_in,
                              void* d_out, int out_size, void* d_ws,
                              size_t ws_size, hipStream_t stream) {
  (void)in_sizes; (void)n_in; (void)out_size; (void)ws_size;
  const float* h  = (const float*)d_in[0];   // [8,2048,256]
  const float* W  = (const float*)d_in[1];   // [64,256]
  const float* a  = (const float*)d_in[2];   // [128,1]
  const int* adj  = (const int*)d_in[3];     // [8,2048,2048]
  float* out = (float*)d_out;                // [8,2048,64]

  short* whf = (short*)d_ws;                            // 2 MB bf16 frags
  float* wh1 = (float*)((char*)d_ws + 2 * 1024 * 1024); // 64 KB
  float* wh2 = wh1 + 8 * 2048;                          // 64 KB

  k_wh<<<512, 256, 0, stream>>>(h, W, a, whf, wh1, wh2);
  k_attn<<<1024, 256, 0, stream>>>(adj, whf, wh1, wh2, out);
}

// Round 5
// 222.693 us; speedup vs baseline: 1.0179x; 1.0179x over previous
//
#include <hip/hip_runtime.h>
#include <hip/hip_bf16.h>
#include <stdint.h>

// GAT layer, fused.  B=8, N=2048, F_in=256, F_out=64.  FINAL (R2 structure,
// best measured: 223.5 us; R4's nt-load/depth-2-prefetch variant was noise-
// neutral and is reverted for simplicity).
//
//   k_wh  : Wh = h @ W^T (fp32 LDS-tiled), emits Wh1/Wh2 (fp32 -- logits
//           stay full fp32 for precision) and Wh in bf16 MFMA-B-fragment
//           layout (k_attn B-loads = coalesced dwordx4).
//   k_attn: single pass over adj, 16-row tiles, 4 waves split the j-range.
//           exp factoring: exp(leaky(w1+w2)-C) = max(P1*P2[j], N1*N2[j])
//           with P1=exp(cm-C), N1=exp(0.2cm-C) per-row (both <=1) and
//           P2=exp(w2-M2), N2=exp(0.2(w2-M2)) per-j (both <=1, LDS).
//           -> inner loop has NO transcendentals and cannot overflow;
//           l accumulated in the same pass (C is an exact row-max bound
//           because leaky-relu is monotone). P(bf16 A-frag) x Wh(bf16
//           B-frag) via mfma_f32_16x16x32_bf16, fp32 accum; epilogue /l+ELU.
//
// Perf notes (measured): dur_us is dominated by ~195 us of harness
// restore/poison traffic; controllable kernel time ~30 us vs ~26 us floor
// (adj 128 MB @ 6.3 TB/s = 20.3 us is irreducible). nt adj loads and
// deeper prefetch were neutral -> k_attn is at the HBM stream floor.

typedef __attribute__((ext_vector_type(8))) short short8;
typedef __attribute__((ext_vector_type(4))) float f32x4;

#define GAT_ALPHA 0.2f

__device__ __forceinline__ short f2bf(float x) {  // RNE float->bf16 bits
  union { float f; uint32_t u; } v; v.f = x;
  uint32_t r = v.u + 0x7FFFu + ((v.u >> 16) & 1u);
  return (short)(r >> 16);
}

// ---------------------------------------------------------------- kernel 1
// grid 512, block 256. 32 rows/block, K split in two 128-phases.
__global__ __launch_bounds__(256) void k_wh(
    const float* __restrict__ h, const float* __restrict__ W,
    const float* __restrict__ a, short* __restrict__ whf,
    float* __restrict__ wh1, float* __restrict__ wh2)
{
  __shared__ float hl[32 * 132];
  __shared__ float Wl[64 * 132];
  const int tid  = threadIdx.x;
  const int og   = tid & 15;   // output group: o = og + 16c
  const int rg   = tid >> 4;   // row group: rows rg*2 + {0,1}
  const int row0 = blockIdx.x << 5;

  float acc[2][4] = {};

  for (int kp = 0; kp < 2; ++kp) {
    if (kp) __syncthreads();
#pragma unroll
    for (int i = 0; i < 4; ++i) {            // stage h 32x128
      int idx4 = tid + (i << 8);
      int row = idx4 >> 5, kc = idx4 & 31;
      *(float4*)&hl[row * 132 + kc * 4] =
          *(const float4*)&h[(size_t)(row0 + row) * 256 + (kp << 7) + kc * 4];
    }
#pragma unroll
    for (int i = 0; i < 8; ++i) {            // stage W 64x128
      int idx4 = tid + (i << 8);
      int o = idx4 >> 5, kc = idx4 & 31;
      *(float4*)&Wl[o * 132 + kc * 4] =
          *(const float4*)&W[o * 256 + (kp << 7) + kc * 4];
    }
    __syncthreads();
#pragma unroll 4
    for (int kc = 0; kc < 32; ++kc) {
      const int k0 = kc * 4;
      const float4 hv0 = *(const float4*)&hl[(rg * 2 + 0) * 132 + k0];
      const float4 hv1 = *(const float4*)&hl[(rg * 2 + 1) * 132 + k0];
#pragma unroll
      for (int c = 0; c < 4; ++c) {
        const float4 wv = *(const float4*)&Wl[(og + (c << 4)) * 132 + k0];
        acc[0][c] += hv0.x * wv.x + hv0.y * wv.y + hv0.z * wv.z + hv0.w * wv.w;
        acc[1][c] += hv1.x * wv.x + hv1.y * wv.y + hv1.z * wv.z + hv1.w * wv.w;
      }
    }
  }

  float a1v[4], a2v[4];
#pragma unroll
  for (int c = 0; c < 4; ++c) {
    a1v[c] = a[og + (c << 4)];
    a2v[c] = a[64 + og + (c << 4)];
  }
#pragma unroll
  for (int r = 0; r < 2; ++r) {
    const int row = row0 + rg * 2 + r;
    const int bb = row >> 11, j = row & 2047;
    const int s = j >> 5, g2 = (j >> 3) & 3, t = j & 7;
    // B-frag layout: idx = b*131072 + ((s*4 + ot)*64 + g2*16 + og)*8 + t
    const size_t base = ((size_t)bb << 17) +
                        (size_t)((s * 256 + g2 * 16 + og) * 8 + t);
    float p1 = 0.f, p2 = 0.f;
#pragma unroll
    for (int c = 0; c < 4; ++c) {
      whf[base + c * 512] = f2bf(acc[r][c]);
      p1 += acc[r][c] * a1v[c];
      p2 += acc[r][c] * a2v[c];
    }
#pragma unroll
    for (int off = 8; off; off >>= 1) {      // reduce over 16-lane og group
      p1 += __shfl_xor(p1, off);
      p2 += __shfl_xor(p2, off);
    }
    if (og == 0) { wh1[row] = p1; wh2[row] = p2; }
  }
}

// ---------------------------------------------------------------- kernel 2
// grid 1024 (= b * 128 i-tiles of 16 rows), block 256 (4 waves).
// wave w handles j in [w*512, (w+1)*512), all 4 o-tiles, 16 rows.
__global__ __launch_bounds__(256) void k_attn(
    const int* __restrict__ adj, const short* __restrict__ whf,
    const float* __restrict__ wh1, const float* __restrict__ wh2,
    float* __restrict__ out)
{
  const int blk = blockIdx.x;
  const int b   = blk >> 7;
  const int i0  = (blk & 127) << 4;
  const int tid = threadIdx.x;
  const int wave = tid >> 6;
  const int lane = tid & 63;
  const int og = lane & 15;    // A-frag row m
  const int g  = lane >> 4;    // A-frag k-quad

  __shared__ __align__(16) float2 pn[2048];  // {P2,N2} per j; reused as red[]
  __shared__ float lred[64];                 // l partial per (wave,row)
  __shared__ float redm[4];

  // ---- phase 1: block max of Wh2[b,:]
  const float* w2g = wh2 + (b << 11);
  float w2r[8];
  float mp = -3.0e38f;
  {
    const float4 v0 = *(const float4*)&w2g[tid << 3];
    const float4 v1 = *(const float4*)&w2g[(tid << 3) + 4];
    w2r[0] = v0.x; w2r[1] = v0.y; w2r[2] = v0.z; w2r[3] = v0.w;
    w2r[4] = v1.x; w2r[5] = v1.y; w2r[6] = v1.z; w2r[7] = v1.w;
#pragma unroll
    for (int t = 0; t < 8; ++t) mp = fmaxf(mp, w2r[t]);
  }
#pragma unroll
  for (int off = 32; off; off >>= 1) mp = fmaxf(mp, __shfl_xor(mp, off));
  if (lane == 0) redm[wave] = mp;
  __syncthreads();
  const float M2 = fmaxf(fmaxf(redm[0], redm[1]), fmaxf(redm[2], redm[3]));

  // ---- phase 2: stage {P2,N2} per j
  {
    float4 st[4];
#pragma unroll
    for (int t = 0; t < 4; ++t) {
      st[t].x = __expf(w2r[2 * t] - M2);
      st[t].y = __expf(GAT_ALPHA * (w2r[2 * t] - M2));
      st[t].z = __expf(w2r[2 * t + 1] - M2);
      st[t].w = __expf(GAT_ALPHA * (w2r[2 * t + 1] - M2));
    }
#pragma unroll
    for (int t = 0; t < 4; ++t)
      *(float4*)&pn[(tid << 3) + 2 * t] = st[t];
  }

  // ---- per-row constants
  const int irow = i0 + og;
  const float w1 = wh1[(b << 11) + irow];
  const float cm = w1 + M2;
  const float C  = fmaxf(cm, GAT_ALPHA * cm);   // exact row-max upper bound
  const float P1 = __expf(cm - C);              // <= 1
  const float N1 = __expf(GAT_ALPHA * cm - C);  // <= 1
  __syncthreads();

  // ---- main loop: 16 steps of 32 j
  const int jbase0 = wave << 9;
  const int* __restrict__ arow =
      adj + ((size_t)((b << 11) + irow) << 11) + jbase0 + (g << 3);
  const short8* __restrict__ fb = (const short8*)whf + (b << 14);
  const float4* __restrict__ pn4 = (const float4*)pn;
  const int pnb = ((jbase0 >> 1) + (g << 2));
  const int fo0 = (jbase0 >> 5) << 2;

  f32x4 acc[4] = {{0.f,0.f,0.f,0.f},{0.f,0.f,0.f,0.f},
                  {0.f,0.f,0.f,0.f},{0.f,0.f,0.f,0.f}};
  float lsum = 0.f;

  int4 A0 = *(const int4*)arow;
  int4 A1 = *(const int4*)(arow + 4);
  short8 B0 = fb[(fo0 + 0) * 64 + lane];
  short8 B1 = fb[(fo0 + 1) * 64 + lane];
  short8 B2 = fb[(fo0 + 2) * 64 + lane];
  short8 B3 = fb[(fo0 + 3) * 64 + lane];

  union Frag { short8 s; __hip_bfloat162 h[4]; };

  auto step = [&](const int4 cA0, const int4 cA1, const short8 cB0,
                  const short8 cB1, const short8 cB2, const short8 cB3,
                  const int s) {
    const float4 q0 = pn4[pnb + (s << 4) + 0];  // {P2 j0, N2 j0, P2 j1, N2 j1}
    const float4 q1 = pn4[pnb + (s << 4) + 1];
    const float4 q2 = pn4[pnb + (s << 4) + 2];
    const float4 q3 = pn4[pnb + (s << 4) + 3];
    float p[8];
    p[0] = fmaxf(P1 * q0.x, N1 * q0.y); p[1] = fmaxf(P1 * q0.z, N1 * q0.w);
    p[2] = fmaxf(P1 * q1.x, N1 * q1.y); p[3] = fmaxf(P1 * q1.z, N1 * q1.w);
    p[4] = fmaxf(P1 * q2.x, N1 * q2.y); p[5] = fmaxf(P1 * q2.z, N1 * q2.w);
    p[6] = fmaxf(P1 * q3.x, N1 * q3.y); p[7] = fmaxf(P1 * q3.z, N1 * q3.w);
    p[0] = (cA0.x > 0) ? p[0] : 0.f;  p[1] = (cA0.y > 0) ? p[1] : 0.f;
    p[2] = (cA0.z > 0) ? p[2] : 0.f;  p[3] = (cA0.w > 0) ? p[3] : 0.f;
    p[4] = (cA1.x > 0) ? p[4] : 0.f;  p[5] = (cA1.y > 0) ? p[5] : 0.f;
    p[6] = (cA1.z > 0) ? p[6] : 0.f;  p[7] = (cA1.w > 0) ? p[7] : 0.f;
    lsum += ((p[0] + p[1]) + (p[2] + p[3])) + ((p[4] + p[5]) + (p[6] + p[7]));
    Frag af;
#pragma unroll
    for (int t = 0; t < 4; ++t)
      af.h[t] = __float22bfloat162_rn(float2{p[2 * t], p[2 * t + 1]});
    acc[0] = __builtin_amdgcn_mfma_f32_16x16x32_bf16(af.s, cB0, acc[0], 0, 0, 0);
    acc[1] = __builtin_amdgcn_mfma_f32_16x16x32_bf16(af.s, cB1, acc[1], 0, 0, 0);
    acc[2] = __builtin_amdgcn_mfma_f32_16x16x32_bf16(af.s, cB2, acc[2], 0, 0, 0);
    acc[3] = __builtin_amdgcn_mfma_f32_16x16x32_bf16(af.s, cB3, acc[3], 0, 0, 0);
  };

  for (int s = 0; s < 15; ++s) {
    const int* an = arow + ((s + 1) << 5);
    const int4 nA0 = *(const int4*)an;
    const int4 nA1 = *(const int4*)(an + 4);
    const int fo = fo0 + ((s + 1) << 2);
    const short8 nB0 = fb[(fo + 0) * 64 + lane];
    const short8 nB1 = fb[(fo + 1) * 64 + lane];
    const short8 nB2 = fb[(fo + 2) * 64 + lane];
    const short8 nB3 = fb[(fo + 3) * 64 + lane];
    step(A0, A1, B0, B1, B2, B3, s);
    A0 = nA0; A1 = nA1; B0 = nB0; B1 = nB1; B2 = nB2; B3 = nB3;
  }
  step(A0, A1, B0, B1, B2, B3, 15);

  // ---- combine j-partials across waves (reuse pn as red[4][16][64])
  lsum += __shfl_xor(lsum, 16);
  lsum += __shfl_xor(lsum, 32);
  if (g == 0) lred[(wave << 4) + og] = lsum;

  __syncthreads();                       // all waves done reading pn
  float* red = (float*)pn;               // red[w*1024 + row*64 + col]
#pragma unroll
  for (int ot = 0; ot < 4; ++ot)
#pragma unroll
    for (int q = 0; q < 4; ++q)
      red[(wave << 10) + ((g << 2) + q) * 64 + (ot << 4) + og] = acc[ot][q];
  __syncthreads();

  // ---- final reduce + epilogue: thread -> col = tid&63, rows rb*4+q
  const int col = tid & 63;
  const int rb  = tid >> 6;
#pragma unroll
  for (int q = 0; q < 4; ++q) {
    const int row = (rb << 2) + q;
    float s = red[row * 64 + col] + red[1024 + row * 64 + col] +
              red[2048 + row * 64 + col] + red[3072 + row * 64 + col];
    const float l = lred[row] + lred[16 + row] + lred[32 + row] + lred[48 + row];
    float v = s / l;
    v = v > 0.f ? v : __expf(v) - 1.0f;          // ELU (alpha=1)
    out[((size_t)((b << 11) + i0 + row) << 6) + col] = v;
  }
}

extern "C" void kernel_launch(void* const* d_in, const int* in_sizes, int n_in,
                              void* d_out, int out_size, void* d_ws,
                              size_t ws_size, hipStream_t stream) {
  (void)in_sizes; (void)n_in; (void)out_size; (void)ws_size;
  const float* h  = (const float*)d_in[0];   // [8,2048,256]
  const float* W  = (const float*)d_in[1];   // [64,256]
  const float* a  = (const float*)d_in[2];   // [128,1]
  const int* adj  = (const int*)d_in[3];     // [8,2048,2048]
  float* out = (float*)d_out;                // [8,2048,64]

  short* whf = (short*)d_ws;                            // 2 MB bf16 frags
  float* wh1 = (float*)((char*)d_ws + 2 * 1024 * 1024); // 64 KB
  float* wh2 = wh1 + 8 * 2048;                          // 64 KB

  k_wh<<<512, 256, 0, stream>>>(h, W, a, whf, wh1, wh2);
  k_attn<<<1024, 256, 0, stream>>>(adj, whf, wh1, wh2, out);
}